// Round 3
// baseline (401.361 us; speedup 1.0000x reference)
//
#include <hip/hip_runtime.h>
#include <hip/hip_bf16.h>
#include <cstdint>
#include <cmath>

#define DEV __device__ __forceinline__

typedef float f32x4 __attribute__((ext_vector_type(4)));
typedef __bf16 bf16x8 __attribute__((ext_vector_type(8)));
typedef unsigned short u16;
typedef u16 u16x8 __attribute__((ext_vector_type(8)));
typedef u16 u16x4 __attribute__((ext_vector_type(4)));

DEV u16 f2bf(float f) {
  union { float f; uint32_t u; } x{f};
  uint32_t r = x.u + 0x7FFFu + ((x.u >> 16) & 1u);
  return (u16)(r >> 16);
}

DEV void gl_lds16(const u16* g, u16* l) {
  __builtin_amdgcn_global_load_lds((const __attribute__((address_space(1))) void*)g,
                                   (__attribute__((address_space(3))) void*)l, 16, 0, 0);
}

// ---------------- f32 -> bf16 convert ----------------
__global__ __launch_bounds__(256) void k_cvt(const float* __restrict__ s,
                                             u16* __restrict__ d, int n) {
  int step = gridDim.x * blockDim.x * 4;
  for (int i = (blockIdx.x * blockDim.x + threadIdx.x) * 4; i < n; i += step) {
    float4 v = *reinterpret_cast<const float4*>(s + i);
    u16x4 o;
    o[0] = f2bf(v.x); o[1] = f2bf(v.y); o[2] = f2bf(v.z); o[3] = f2bf(v.w);
    *reinterpret_cast<u16x4*>(d + i) = o;
  }
}

// ---------------- GEMM: C[M,N] = A[M,K] @ B[N,K]^T (+bias, epilogue) -------
// MODE 0: bf16 out = (acc+bias)*oscale ; MODE 1: bf16 out = relu(acc+bias)
// MODE 2: f32 out = acc+bias+res
template <int MODE>
DEV void gemm_core(const u16* __restrict__ A, const u16* __restrict__ B,
                   const float* __restrict__ bias, const float* __restrict__ res,
                   void* __restrict__ C, int N, int K, int m0, int n0,
                   float oscale) {
  __shared__ u16 sA[2][128 * 32];
  __shared__ u16 sB[2][128 * 32];
  const int tid = threadIdx.x;
  const int w = tid >> 6, l = tid & 63;
  const int lr = l & 15, lg = l >> 4;
  const int wr = (w >> 1) * 64, wc = (w & 1) * 64;

  f32x4 acc[4][4] = {};

  const int nt = K >> 5;
  const int sr = w * 16 + (l >> 2);  // staging row (within 64-row half)
  const int sc = (l & 3) * 8;        // staging col (elements)

  auto stage = [&](int buf, int t) {
    const u16* ga = A + (size_t)(m0 + sr) * K + t * 32 + sc;
    const u16* gb = B + (size_t)(n0 + sr) * K + t * 32 + sc;
    gl_lds16(ga, &sA[buf][w * 512]);
    gl_lds16(ga + (size_t)64 * K, &sA[buf][2048 + w * 512]);
    gl_lds16(gb, &sB[buf][w * 512]);
    gl_lds16(gb + (size_t)64 * K, &sB[buf][2048 + w * 512]);
  };

  auto compute = [&](int buf) {
    bf16x8 af[4], bfr[4];
#pragma unroll
    for (int mf = 0; mf < 4; ++mf)
      af[mf] = *(const bf16x8*)&sA[buf][(wr + mf * 16 + lr) * 32 + lg * 8];
#pragma unroll
    for (int nf = 0; nf < 4; ++nf)
      bfr[nf] = *(const bf16x8*)&sB[buf][(wc + nf * 16 + lr) * 32 + lg * 8];
#pragma unroll
    for (int mf = 0; mf < 4; ++mf)
#pragma unroll
      for (int nf = 0; nf < 4; ++nf)
        acc[mf][nf] = __builtin_amdgcn_mfma_f32_16x16x32_bf16(af[mf], bfr[nf],
                                                              acc[mf][nf], 0, 0, 0);
  };

  stage(0, 0);
  __syncthreads();
  int cur = 0;
  for (int t = 0; t < nt - 1; ++t) {
    stage(cur ^ 1, t + 1);
    compute(cur);
    __syncthreads();
    cur ^= 1;
  }
  compute(cur);

#pragma unroll
  for (int nf = 0; nf < 4; ++nf) {
    const int col = n0 + wc + nf * 16 + lr;
    const float bv = bias[col];
#pragma unroll
    for (int mf = 0; mf < 4; ++mf) {
      const int row0 = m0 + wr + mf * 16 + lg * 4;
#pragma unroll
      for (int r = 0; r < 4; ++r) {
        float v = acc[mf][nf][r] + bv;
        if (MODE == 0) v *= oscale;
        if (MODE == 1) v = fmaxf(v, 0.0f);
        const size_t idx = (size_t)(row0 + r) * N + col;
        if (MODE == 2) ((float*)C)[idx] = v + res[idx];
        else ((u16*)C)[idx] = f2bf(v);
      }
    }
  }
}

template <int MODE>
__global__ __launch_bounds__(256) void k_gemm(const u16* __restrict__ A,
                                              const u16* __restrict__ B,
                                              const float* __restrict__ bias,
                                              const float* __restrict__ res,
                                              void* __restrict__ C, int N, int K) {
  gemm_core<MODE>(A, B, bias, res, C, N, K, blockIdx.x * 128, blockIdx.y * 128, 1.0f);
}

__global__ __launch_bounds__(256) void k_gemm_qkv(
    const u16* __restrict__ A, const u16* __restrict__ B0, const u16* __restrict__ B1,
    const u16* __restrict__ B2, const float* __restrict__ c0,
    const float* __restrict__ c1, const float* __restrict__ c2,
    u16* __restrict__ O0, u16* __restrict__ O1, u16* __restrict__ O2) {
  const int z = blockIdx.z;
  const u16* B = (z == 0) ? B0 : (z == 1) ? B1 : B2;
  const float* bias = (z == 0) ? c0 : (z == 1) ? c1 : c2;
  u16* O = (z == 0) ? O0 : (z == 1) ? O1 : O2;
  // Q is pre-scaled by log2(e) so attention can use exp2 directly (exact:
  // softmax(s) == exp2(s*log2e - m2)/sum, base change is a no-op).
  const float sc = (z == 0) ? 1.44269504f : 1.0f;
  gemm_core<0>(A, B, bias, nullptr, O, 1024, 1024, blockIdx.x * 128,
               blockIdx.y * 128, sc);
}

// ---------------- flash attention (no pre-scale, /8 after PV) --------------
// Q was pre-scaled by log2e; softmax runs in exp2 domain.
// grid: 1024 blocks (XCD-swizzled), 256 thr = 4 waves x 16 q-rows, KVBLK=64
__global__ __launch_bounds__(256) void k_attn(const u16* __restrict__ Q,
                                              const u16* __restrict__ K,
                                              const u16* __restrict__ V,
                                              u16* __restrict__ Z) {
  // XCD-bijective swizzle: 1024 = 8 XCD * 128; each XCD gets 4 whole heads
  // so K/V tiles stay L2-resident per XCD.
  const int id = blockIdx.x;
  const int virt = (id & 7) * 128 + (id >> 3);
  const int bh = virt >> 5;   // 0..31 (b*16+h)
  const int qt = virt & 31;   // 0..31, 64-row q-tile
  const int b = bh >> 4, h = bh & 15;
  const int tid = threadIdx.x;
  const int w = tid >> 6, l = tid & 63;
  const int lr = l & 15, lg = l >> 4;

  __shared__ u16 VT[64][64];       // V^T tile, XOR-swizzled (8 KB)
  __shared__ u16 PL[4][16 * 64];   // per-wave P (16 q-rows), XOR-swizzled (8 KB)

  const size_t rb = (size_t)b * 2048;
  const int c0 = h * 64;
  const int q0 = qt * 64 + w * 16;

  bf16x8 qa[2];
#pragma unroll
  for (int kf = 0; kf < 2; ++kf)
    qa[kf] = *(const bf16x8*)(Q + (rb + q0 + lr) * 1024 + c0 + kf * 32 + lg * 8);

  f32x4 zacc[4] = {};
  float mrun[4], lrun[4];
#pragma unroll
  for (int r = 0; r < 4; ++r) { mrun[r] = -1e30f; lrun[r] = 0.f; }

  const int vp = tid & 31, vd0 = (tid >> 5) * 8;

  for (int t = 0; t < 32; ++t) {
    const int kv0 = t * 64;
    __syncthreads();  // prior PV reads done before re-staging VT
    {  // stage V^T (pack kv-pairs into b32, swizzle kv by dh bits 2-3)
      const u16* v0 = V + (rb + kv0 + 2 * vp) * 1024 + c0 + vd0;
      u16x8 a0 = *(const u16x8*)v0;
      u16x8 a1 = *(const u16x8*)(v0 + 1024);
#pragma unroll
      for (int i = 0; i < 8; ++i) {
        const int dh = vd0 + i;
        const int kvs = (2 * vp) ^ (((dh >> 2) & 3) << 4);
        uint32_t pk = (uint32_t)a0[i] | ((uint32_t)a1[i] << 16);
        *(uint32_t*)&VT[dh][kvs] = pk;
      }
    }
    // QK^T (K fragments straight from global/L2)
    f32x4 s[4] = {};
#pragma unroll
    for (int kf = 0; kf < 2; ++kf) {
      bf16x8 kb[4];
#pragma unroll
      for (int nf = 0; nf < 4; ++nf)
        kb[nf] = *(const bf16x8*)(K + (rb + kv0 + nf * 16 + lr) * 1024 + c0 + kf * 32 + lg * 8);
#pragma unroll
      for (int nf = 0; nf < 4; ++nf)
        s[nf] = __builtin_amdgcn_mfma_f32_16x16x32_bf16(qa[kf], kb[nf], s[nf], 0, 0, 0);
    }
    // online softmax in exp2 domain
    f32x4 tm = s[0];
#pragma unroll
    for (int nf = 1; nf < 4; ++nf)
#pragma unroll
      for (int r = 0; r < 4; ++r) tm[r] = fmaxf(tm[r], s[nf][r]);
#pragma unroll
    for (int st = 1; st < 16; st <<= 1)
#pragma unroll
      for (int r = 0; r < 4; ++r) tm[r] = fmaxf(tm[r], __shfl_xor(tm[r], st, 64));
    // defer-max: only rescale when some row's max grew by > 8 (log2 units,
    // so deferred P values stay <= 2^8 — fine in bf16).
    int need = 0;
#pragma unroll
    for (int r = 0; r < 4; ++r) need |= (tm[r] > mrun[r] + 8.0f) ? 1 : 0;
    if (__any(need)) {
      float sc[4];
#pragma unroll
      for (int r = 0; r < 4; ++r) {
        float mn = fmaxf(mrun[r], tm[r]);
        sc[r] = exp2f(mrun[r] - mn);
        mrun[r] = mn;
        lrun[r] *= sc[r];
      }
#pragma unroll
      for (int nf = 0; nf < 4; ++nf)
#pragma unroll
        for (int r = 0; r < 4; ++r) zacc[nf][r] *= sc[r];
    }
#pragma unroll
    for (int nf = 0; nf < 4; ++nf)
#pragma unroll
      for (int r = 0; r < 4; ++r) {
        float p = exp2f(s[nf][r] - mrun[r]);
        lrun[r] += p;
        const int q = lg * 4 + r;
        const int kv = (nf * 16 + lr) ^ (lg << 4);
        PL[w][q * 64 + kv] = f2bf(p);
      }
    __syncthreads();  // VT + P visible
    // PV
#pragma unroll
    for (int kf2 = 0; kf2 < 2; ++kf2) {
      const int kvp = (kf2 * 32 + lg * 8) ^ (((lr >> 2) & 3) << 4);
      bf16x8 pa = *(const bf16x8*)&PL[w][lr * 64 + kvp];
      bf16x8 vb[4];
#pragma unroll
      for (int nf = 0; nf < 4; ++nf) {
        const int dh = nf * 16 + lr;
        const int kvb = (kf2 * 32 + lg * 8) ^ (((dh >> 2) & 3) << 4);
        vb[nf] = *(const bf16x8*)&VT[dh][kvb];
      }
#pragma unroll
      for (int nf = 0; nf < 4; ++nf)
        zacc[nf] = __builtin_amdgcn_mfma_f32_16x16x32_bf16(pa, vb[nf], zacc[nf], 0, 0, 0);
    }
  }

  // complete softmax denominator across the 16-lane lr group (mrun is
  // group-uniform, so partials are consistently scaled).
#pragma unroll
  for (int st = 1; st < 16; st <<= 1)
#pragma unroll
    for (int r = 0; r < 4; ++r)
      lrun[r] += __shfl_xor(lrun[r], st, 64);

#pragma unroll
  for (int r = 0; r < 4; ++r) {
    const float inv = 0.125f / lrun[r];  // /sqrt(64) folded in
    const size_t row = rb + q0 + lg * 4 + r;
#pragma unroll
    for (int nf = 0; nf < 4; ++nf)
      Z[row * 1024 + c0 + nf * 16 + lr] = f2bf(zacc[nf][r] * inv);
  }
}

// ---------------- row LayerNorm (1024 cols) ----------------
template <bool WBF>
__global__ __launch_bounds__(256) void k_ln(const float* __restrict__ x,
                                            const float* __restrict__ g,
                                            const float* __restrict__ be,
                                            float* __restrict__ of,
                                            u16* __restrict__ ob) {
  const int row = blockIdx.x;
  const int tid = threadIdx.x;
  const float* xr = x + (size_t)row * 1024;
  float4 v = *(const float4*)(xr + tid * 4);
  float s = v.x + v.y + v.z + v.w;
  float s2 = v.x * v.x + v.y * v.y + v.z * v.z + v.w * v.w;
#pragma unroll
  for (int st = 1; st < 64; st <<= 1) {
    s += __shfl_xor(s, st, 64);
    s2 += __shfl_xor(s2, st, 64);
  }
  __shared__ float ps[8];
  if ((tid & 63) == 0) { ps[tid >> 6] = s; ps[4 + (tid >> 6)] = s2; }
  __syncthreads();
  s = ps[0] + ps[1] + ps[2] + ps[3];
  s2 = ps[4] + ps[5] + ps[6] + ps[7];
  const float mu = s * 0.0009765625f;
  const float var = s2 * 0.0009765625f - mu * mu;
  const float rs = rsqrtf(var + 1e-5f);
  float4 gg = *(const float4*)(g + tid * 4);
  float4 bb = *(const float4*)(be + tid * 4);
  float4 o;
  o.x = (v.x - mu) * rs * gg.x + bb.x;
  o.y = (v.y - mu) * rs * gg.y + bb.y;
  o.z = (v.z - mu) * rs * gg.z + bb.z;
  o.w = (v.w - mu) * rs * gg.w + bb.w;
  *(float4*)(of + (size_t)row * 1024 + tid * 4) = o;
  if (WBF) {
    u16x4 q;
    q[0] = f2bf(o.x); q[1] = f2bf(o.y); q[2] = f2bf(o.z); q[3] = f2bf(o.w);
    *(u16x4*)(ob + (size_t)row * 1024 + tid * 4) = q;
  }
}

// ---------------- launch ----------------
extern "C" void kernel_launch(void* const* d_in, const int* in_sizes, int n_in,
                              void* d_out, int out_size, void* d_ws, size_t ws_size,
                              hipStream_t stream) {
  const float* emb = (const float*)d_in[0];
  const float* Wq  = (const float*)d_in[1];
  const float* bq  = (const float*)d_in[2];
  const float* Wk  = (const float*)d_in[3];
  const float* bk  = (const float*)d_in[4];
  const float* Wv  = (const float*)d_in[5];
  const float* bv  = (const float*)d_in[6];
  const float* W0  = (const float*)d_in[7];
  const float* b0  = (const float*)d_in[8];
  const float* g1  = (const float*)d_in[9];
  const float* be1 = (const float*)d_in[10];
  const float* W1  = (const float*)d_in[11];
  const float* b1  = (const float*)d_in[12];
  const float* W2  = (const float*)d_in[13];
  const float* b2  = (const float*)d_in[14];
  const float* g2  = (const float*)d_in[15];
  const float* be2 = (const float*)d_in[16];

  char* p = (char*)d_ws;
  auto alloc = [&](size_t bytes) { char* r = p; p += bytes; return r; };
  u16* embb = (u16*)alloc(8u << 20);
  u16* Wqb  = (u16*)alloc(2u << 20);
  u16* Wkb  = (u16*)alloc(2u << 20);
  u16* Wvb  = (u16*)alloc(2u << 20);
  u16* W0b  = (u16*)alloc(2u << 20);
  u16* W1b  = (u16*)alloc(8u << 20);
  u16* W2b  = (u16*)alloc(8u << 20);
  u16* Qb   = (u16*)alloc(8u << 20);
  u16* Kb   = (u16*)alloc(8u << 20);
  u16* Vb   = (u16*)alloc(8u << 20);
  u16* Zb   = (u16*)alloc(8u << 20);
  float* y1 = (float*)alloc(16u << 20);   // reused as y2 later
  float* o1f = (float*)alloc(16u << 20);
  u16* o1b  = (u16*)alloc(8u << 20);
  u16* hb   = (u16*)alloc(32u << 20);

  auto cvt = [&](const float* s, u16* d, int n) {
    int blk = (n / 4 + 255) / 256;
    if (blk > 4096) blk = 4096;
    k_cvt<<<blk, 256, 0, stream>>>(s, d, n);
  };
  cvt(emb, embb, 4096 * 1024);
  cvt(Wq, Wqb, 1024 * 1024);
  cvt(Wk, Wkb, 1024 * 1024);
  cvt(Wv, Wvb, 1024 * 1024);
  cvt(W0, W0b, 1024 * 1024);
  cvt(W1, W1b, 4096 * 1024);
  cvt(W2, W2b, 4096 * 1024);

  k_gemm_qkv<<<dim3(32, 8, 3), 256, 0, stream>>>(embb, Wqb, Wkb, Wvb, bq, bk, bv,
                                                 Qb, Kb, Vb);
  k_attn<<<dim3(1024), 256, 0, stream>>>(Qb, Kb, Vb, Zb);
  // y1 = Z @ W0^T + b0 + emb
  k_gemm<2><<<dim3(32, 8), 256, 0, stream>>>(Zb, W0b, b0, emb, y1, 1024, 1024);
  k_ln<true><<<4096, 256, 0, stream>>>(y1, g1, be1, o1f, o1b);
  // h = relu(out1 @ W1^T + b1)
  k_gemm<1><<<dim3(32, 32), 256, 0, stream>>>(o1b, W1b, b1, nullptr, hb, 4096, 1024);
  // y2 = h @ W2^T + b2 + out1   (reuse y1 buffer)
  k_gemm<2><<<dim3(32, 8), 256, 0, stream>>>(hb, W2b, b2, o1f, y1, 1024, 4096);
  k_ln<false><<<4096, 256, 0, stream>>>(y1, g2, be2, (float*)d_out, nullptr);
}

// Round 4
// 352.841 us; speedup vs baseline: 1.1375x; 1.1375x over previous
//
#include <hip/hip_runtime.h>
#include <hip/hip_bf16.h>
#include <cstdint>
#include <cmath>

#define DEV __device__ __forceinline__

typedef float f32x4 __attribute__((ext_vector_type(4)));
typedef __bf16 bf16x8 __attribute__((ext_vector_type(8)));
typedef unsigned short u16;
typedef u16 u16x8 __attribute__((ext_vector_type(8)));
typedef u16 u16x4 __attribute__((ext_vector_type(4)));

DEV u16 f2bf(float f) {
  union { float f; uint32_t u; } x{f};
  uint32_t r = x.u + 0x7FFFu + ((x.u >> 16) & 1u);
  return (u16)(r >> 16);
}

DEV void gl_lds16(const u16* g, u16* l) {
  __builtin_amdgcn_global_load_lds((const __attribute__((address_space(1))) void*)g,
                                   (__attribute__((address_space(3))) void*)l, 16, 0, 0);
}

// ---------------- f32 -> bf16 convert ----------------
__global__ __launch_bounds__(256) void k_cvt(const float* __restrict__ s,
                                             u16* __restrict__ d, int n) {
  int step = gridDim.x * blockDim.x * 4;
  for (int i = (blockIdx.x * blockDim.x + threadIdx.x) * 4; i < n; i += step) {
    float4 v = *reinterpret_cast<const float4*>(s + i);
    u16x4 o;
    o[0] = f2bf(v.x); o[1] = f2bf(v.y); o[2] = f2bf(v.z); o[3] = f2bf(v.w);
    *reinterpret_cast<u16x4*>(d + i) = o;
  }
}

// ---------------- GEMM: C[M,N] = A[M,K] @ B[N,K]^T (+bias, epilogue) -------
// MODE 0: bf16 out = (acc+bias)*oscale ; MODE 1: bf16 out = relu(acc+bias)
// MODE 2: f32 out = acc+bias+res
template <int MODE>
DEV void gemm_core(const u16* __restrict__ A, const u16* __restrict__ B,
                   const float* __restrict__ bias, const float* __restrict__ res,
                   void* __restrict__ C, int N, int K, int m0, int n0,
                   float oscale) {
  __shared__ u16 sA[2][128 * 32];
  __shared__ u16 sB[2][128 * 32];
  const int tid = threadIdx.x;
  const int w = tid >> 6, l = tid & 63;
  const int lr = l & 15, lg = l >> 4;
  const int wr = (w >> 1) * 64, wc = (w & 1) * 64;

  f32x4 acc[4][4] = {};

  const int nt = K >> 5;
  const int sr = w * 16 + (l >> 2);  // staging row (within 64-row half)
  const int sc = (l & 3) * 8;        // staging col (elements)

  auto stage = [&](int buf, int t) {
    const u16* ga = A + (size_t)(m0 + sr) * K + t * 32 + sc;
    const u16* gb = B + (size_t)(n0 + sr) * K + t * 32 + sc;
    gl_lds16(ga, &sA[buf][w * 512]);
    gl_lds16(ga + (size_t)64 * K, &sA[buf][2048 + w * 512]);
    gl_lds16(gb, &sB[buf][w * 512]);
    gl_lds16(gb + (size_t)64 * K, &sB[buf][2048 + w * 512]);
  };

  auto compute = [&](int buf) {
    bf16x8 af[4], bfr[4];
#pragma unroll
    for (int mf = 0; mf < 4; ++mf)
      af[mf] = *(const bf16x8*)&sA[buf][(wr + mf * 16 + lr) * 32 + lg * 8];
#pragma unroll
    for (int nf = 0; nf < 4; ++nf)
      bfr[nf] = *(const bf16x8*)&sB[buf][(wc + nf * 16 + lr) * 32 + lg * 8];
#pragma unroll
    for (int mf = 0; mf < 4; ++mf)
#pragma unroll
      for (int nf = 0; nf < 4; ++nf)
        acc[mf][nf] = __builtin_amdgcn_mfma_f32_16x16x32_bf16(af[mf], bfr[nf],
                                                              acc[mf][nf], 0, 0, 0);
  };

  stage(0, 0);
  __syncthreads();
  int cur = 0;
  for (int t = 0; t < nt - 1; ++t) {
    stage(cur ^ 1, t + 1);
    compute(cur);
    __syncthreads();
    cur ^= 1;
  }
  compute(cur);

#pragma unroll
  for (int nf = 0; nf < 4; ++nf) {
    const int col = n0 + wc + nf * 16 + lr;
    const float bv = bias[col];
#pragma unroll
    for (int mf = 0; mf < 4; ++mf) {
      const int row0 = m0 + wr + mf * 16 + lg * 4;
#pragma unroll
      for (int r = 0; r < 4; ++r) {
        float v = acc[mf][nf][r] + bv;
        if (MODE == 0) v *= oscale;
        if (MODE == 1) v = fmaxf(v, 0.0f);
        const size_t idx = (size_t)(row0 + r) * N + col;
        if (MODE == 2) ((float*)C)[idx] = v + res[idx];
        else ((u16*)C)[idx] = f2bf(v);
      }
    }
  }
}

template <int MODE>
__global__ __launch_bounds__(256) void k_gemm(const u16* __restrict__ A,
                                              const u16* __restrict__ B,
                                              const float* __restrict__ bias,
                                              const float* __restrict__ res,
                                              void* __restrict__ C, int N, int K) {
  gemm_core<MODE>(A, B, bias, res, C, N, K, blockIdx.x * 128, blockIdx.y * 128, 1.0f);
}

__global__ __launch_bounds__(256) void k_gemm_qkv(
    const u16* __restrict__ A, const u16* __restrict__ B0, const u16* __restrict__ B1,
    const u16* __restrict__ B2, const float* __restrict__ c0,
    const float* __restrict__ c1, const float* __restrict__ c2,
    u16* __restrict__ O0, u16* __restrict__ O1, u16* __restrict__ O2) {
  const int z = blockIdx.z;
  const u16* B = (z == 0) ? B0 : (z == 1) ? B1 : B2;
  const float* bias = (z == 0) ? c0 : (z == 1) ? c1 : c2;
  u16* O = (z == 0) ? O0 : (z == 1) ? O1 : O2;
  // Q is pre-scaled by log2(e) so attention can use exp2 directly (exact:
  // softmax(s) == exp2(s*log2e - m2)/sum, base change is a no-op).
  const float sc = (z == 0) ? 1.44269504f : 1.0f;
  gemm_core<0>(A, B, bias, nullptr, O, 1024, 1024, blockIdx.x * 128,
               blockIdx.y * 128, sc);
}

// ---------------- flash attention ------------------------------------------
// Q pre-scaled by log2e (exp2-domain softmax). 128 q-rows/block (4 waves x 32),
// 512 blocks XCD-swizzled. K staged via async global_load_lds with chunk-XOR
// pre-swizzled SOURCE (linear LDS dest), double-buffered; V^T reg-staged
// double-buffered; ONE barrier per kv-tile.
__global__ __launch_bounds__(256) void k_attn(const u16* __restrict__ Q,
                                              const u16* __restrict__ K,
                                              const u16* __restrict__ V,
                                              u16* __restrict__ Z) {
  // 512 = 8 XCD * 64: bijective swizzle; 64 consecutive virt per XCD = 4
  // whole (b,h) heads -> K/V L2-resident per XCD.
  const int id = blockIdx.x;
  const int virt = (id & 7) * 64 + (id >> 3);
  const int bh = virt >> 4;   // 0..31
  const int qt = virt & 15;   // 16 q-tiles of 128 rows
  const int b = bh >> 4, h = bh & 15;
  const int tid = threadIdx.x;
  const int w = tid >> 6, l = tid & 63;
  const int lr = l & 15, lg = l >> 4;

  __shared__ u16 Kl[2][64 * 64];   // K tile, chunk-XOR swizzled (16 KB)
  __shared__ u16 VT[2][64 * 64];   // V^T tile, XOR-swizzled (16 KB)
  __shared__ u16 PL[4][32 * 64];   // per-wave P (32 q-rows) (16 KB)

  const size_t rb = (size_t)b * 2048;
  const int c0 = h * 64;
  const int q0 = qt * 128 + w * 32;

  bf16x8 qa[2][2];
#pragma unroll
  for (int mf = 0; mf < 2; ++mf)
#pragma unroll
    for (int kf = 0; kf < 2; ++kf)
      qa[mf][kf] = *(const bf16x8*)(Q + (rb + q0 + mf * 16 + lr) * 1024 + c0 + kf * 32 + lg * 8);

  f32x4 zacc[2][4] = {};
  float mrun[2][4], lrun[2][4];
#pragma unroll
  for (int mf = 0; mf < 2; ++mf)
#pragma unroll
    for (int r = 0; r < 4; ++r) { mrun[mf][r] = -1e30f; lrun[mf][r] = 0.f; }

  // K staging geometry: wave w stages rows 16w..16w+15 (2 calls x 1 KB).
  // LDS[kv][c] (c = 16B chunk 0..7) holds global dh-chunk (c ^ (kv&7)) so
  // the strided b128 fragment reads are bank-conflict-free.
  const int skv = w * 16 + (l >> 3);
  const int sc8 = l & 7;
  auto stage_k = [&](int p, int t) {
#pragma unroll
    for (int cq = 0; cq < 2; ++cq) {
      const int kvl = skv + cq * 8;
      const int dh0 = (sc8 ^ (kvl & 7)) * 8;
      gl_lds16(K + (rb + t * 64 + kvl) * 1024 + c0 + dh0,
               &Kl[p][w * 1024 + cq * 512]);
    }
  };

  // V staging: global -> regs (issue-early), regs -> swizzled VT (write-late)
  const int vp = tid & 31, vd0 = (tid >> 5) * 8;
  u16x8 va0, va1;
  auto vload = [&](int t) {
    const u16* v0 = V + (rb + t * 64 + 2 * vp) * 1024 + c0 + vd0;
    va0 = *(const u16x8*)v0;
    va1 = *(const u16x8*)(v0 + 1024);
  };
  auto vstore = [&](int p) {
#pragma unroll
    for (int i = 0; i < 8; ++i) {
      const int dh = vd0 + i;
      const int kvs = (2 * vp) ^ (((dh >> 2) & 3) << 4);
      uint32_t pk = (uint32_t)va0[i] | ((uint32_t)va1[i] << 16);
      *(uint32_t*)&VT[p][dh * 64 + kvs] = pk;
    }
  };

  stage_k(0, 0);
  vload(0);
  vstore(0);
  __syncthreads();  // K[0] (vmcnt drained here) + VT[0] ready

  for (int t = 0; t < 32; ++t) {
    const int p = t & 1;
    if (t + 1 < 32) {
      stage_k(p ^ 1, t + 1);  // async into the idle buffer
      vload(t + 1);           // global latency hides under QK+softmax
    }
    // QK^T from swizzled K LDS
    f32x4 s[2][4] = {};
    __builtin_amdgcn_s_setprio(1);
#pragma unroll
    for (int kf = 0; kf < 2; ++kf) {
      bf16x8 kb[4];
#pragma unroll
      for (int nf = 0; nf < 4; ++nf)
        kb[nf] = *(const bf16x8*)&Kl[p][(nf * 16 + lr) * 64 + ((kf * 4 + lg) ^ (lr & 7)) * 8];
#pragma unroll
      for (int mf = 0; mf < 2; ++mf)
#pragma unroll
        for (int nf = 0; nf < 4; ++nf)
          s[mf][nf] = __builtin_amdgcn_mfma_f32_16x16x32_bf16(qa[mf][kf], kb[nf], s[mf][nf], 0, 0, 0);
    }
    __builtin_amdgcn_s_setprio(0);
    // online softmax in exp2 domain (defer-max, THR=8 log2 units)
    f32x4 tm[2];
    int need = 0;
#pragma unroll
    for (int mf = 0; mf < 2; ++mf) {
      tm[mf] = s[mf][0];
#pragma unroll
      for (int nf = 1; nf < 4; ++nf)
#pragma unroll
        for (int r = 0; r < 4; ++r) tm[mf][r] = fmaxf(tm[mf][r], s[mf][nf][r]);
#pragma unroll
      for (int st = 1; st < 16; st <<= 1)
#pragma unroll
        for (int r = 0; r < 4; ++r) tm[mf][r] = fmaxf(tm[mf][r], __shfl_xor(tm[mf][r], st, 64));
#pragma unroll
      for (int r = 0; r < 4; ++r) need |= (tm[mf][r] > mrun[mf][r] + 8.0f) ? 1 : 0;
    }
    if (__any(need)) {
#pragma unroll
      for (int mf = 0; mf < 2; ++mf) {
        float sc[4];
#pragma unroll
        for (int r = 0; r < 4; ++r) {
          float mn = fmaxf(mrun[mf][r], tm[mf][r]);
          sc[r] = exp2f(mrun[mf][r] - mn);
          mrun[mf][r] = mn;
          lrun[mf][r] *= sc[r];
        }
#pragma unroll
        for (int nf = 0; nf < 4; ++nf)
#pragma unroll
          for (int r = 0; r < 4; ++r) zacc[mf][nf][r] *= sc[r];
      }
    }
#pragma unroll
    for (int mf = 0; mf < 2; ++mf)
#pragma unroll
      for (int nf = 0; nf < 4; ++nf)
#pragma unroll
        for (int r = 0; r < 4; ++r) {
          float pv = exp2f(s[mf][nf][r] - mrun[mf][r]);
          lrun[mf][r] += pv;
          const int q = mf * 16 + lg * 4 + r;
          const int kv = (nf * 16 + lr) ^ (lg << 4);
          PL[w][q * 64 + kv] = f2bf(pv);
        }
    if (t + 1 < 32) vstore(p ^ 1);  // VT writes overlap with PV below
    // PL is wave-private: in-wave ds ordering only, no barrier needed.
    asm volatile("s_waitcnt lgkmcnt(0)" ::: "memory");
    // PV
    __builtin_amdgcn_s_setprio(1);
#pragma unroll
    for (int kf2 = 0; kf2 < 2; ++kf2) {
      bf16x8 pa[2], vb[4];
#pragma unroll
      for (int mf = 0; mf < 2; ++mf) {
        const int kvp = (kf2 * 32 + lg * 8) ^ (((lr >> 2) & 3) << 4);
        pa[mf] = *(const bf16x8*)&PL[w][(mf * 16 + lr) * 64 + kvp];
      }
#pragma unroll
      for (int nf = 0; nf < 4; ++nf) {
        const int dh = nf * 16 + lr;
        const int kvb = (kf2 * 32 + lg * 8) ^ (((dh >> 2) & 3) << 4);
        vb[nf] = *(const bf16x8*)&VT[p][dh * 64 + kvb];
      }
#pragma unroll
      for (int mf = 0; mf < 2; ++mf)
#pragma unroll
        for (int nf = 0; nf < 4; ++nf)
          zacc[mf][nf] = __builtin_amdgcn_mfma_f32_16x16x32_bf16(pa[mf], vb[nf], zacc[mf][nf], 0, 0, 0);
    }
    __builtin_amdgcn_s_setprio(0);
    __syncthreads();  // next K (vmcnt) + VT buffers ready; protects reuse
  }

  // complete softmax denominator across the 16-lane lr group (mrun is
  // group-uniform, so partials are consistently scaled).
#pragma unroll
  for (int mf = 0; mf < 2; ++mf)
#pragma unroll
    for (int st = 1; st < 16; st <<= 1)
#pragma unroll
      for (int r = 0; r < 4; ++r)
        lrun[mf][r] += __shfl_xor(lrun[mf][r], st, 64);

#pragma unroll
  for (int mf = 0; mf < 2; ++mf)
#pragma unroll
    for (int r = 0; r < 4; ++r) {
      const float inv = 0.125f / lrun[mf][r];  // /sqrt(64) folded in
      const size_t row = rb + q0 + mf * 16 + lg * 4 + r;
#pragma unroll
      for (int nf = 0; nf < 4; ++nf)
        Z[row * 1024 + c0 + nf * 16 + lr] = f2bf(zacc[mf][nf][r] * inv);
    }
}

// ---------------- row LayerNorm (1024 cols) ----------------
template <bool WBF>
__global__ __launch_bounds__(256) void k_ln(const float* __restrict__ x,
                                            const float* __restrict__ g,
                                            const float* __restrict__ be,
                                            float* __restrict__ of,
                                            u16* __restrict__ ob) {
  const int row = blockIdx.x;
  const int tid = threadIdx.x;
  const float* xr = x + (size_t)row * 1024;
  float4 v = *(const float4*)(xr + tid * 4);
  float s = v.x + v.y + v.z + v.w;
  float s2 = v.x * v.x + v.y * v.y + v.z * v.z + v.w * v.w;
#pragma unroll
  for (int st = 1; st < 64; st <<= 1) {
    s += __shfl_xor(s, st, 64);
    s2 += __shfl_xor(s2, st, 64);
  }
  __shared__ float ps[8];
  if ((tid & 63) == 0) { ps[tid >> 6] = s; ps[4 + (tid >> 6)] = s2; }
  __syncthreads();
  s = ps[0] + ps[1] + ps[2] + ps[3];
  s2 = ps[4] + ps[5] + ps[6] + ps[7];
  const float mu = s * 0.0009765625f;
  const float var = s2 * 0.0009765625f - mu * mu;
  const float rs = rsqrtf(var + 1e-5f);
  float4 gg = *(const float4*)(g + tid * 4);
  float4 bb = *(const float4*)(be + tid * 4);
  float4 o;
  o.x = (v.x - mu) * rs * gg.x + bb.x;
  o.y = (v.y - mu) * rs * gg.y + bb.y;
  o.z = (v.z - mu) * rs * gg.z + bb.z;
  o.w = (v.w - mu) * rs * gg.w + bb.w;
  *(float4*)(of + (size_t)row * 1024 + tid * 4) = o;
  if (WBF) {
    u16x4 q;
    q[0] = f2bf(o.x); q[1] = f2bf(o.y); q[2] = f2bf(o.z); q[3] = f2bf(o.w);
    *(u16x4*)(ob + (size_t)row * 1024 + tid * 4) = q;
  }
}

// ---------------- launch ----------------
extern "C" void kernel_launch(void* const* d_in, const int* in_sizes, int n_in,
                              void* d_out, int out_size, void* d_ws, size_t ws_size,
                              hipStream_t stream) {
  const float* emb = (const float*)d_in[0];
  const float* Wq  = (const float*)d_in[1];
  const float* bq  = (const float*)d_in[2];
  const float* Wk  = (const float*)d_in[3];
  const float* bk  = (const float*)d_in[4];
  const float* Wv  = (const float*)d_in[5];
  const float* bv  = (const float*)d_in[6];
  const float* W0  = (const float*)d_in[7];
  const float* b0  = (const float*)d_in[8];
  const float* g1  = (const float*)d_in[9];
  const float* be1 = (const float*)d_in[10];
  const float* W1  = (const float*)d_in[11];
  const float* b1  = (const float*)d_in[12];
  const float* W2  = (const float*)d_in[13];
  const float* b2  = (const float*)d_in[14];
  const float* g2  = (const float*)d_in[15];
  const float* be2 = (const float*)d_in[16];

  char* p = (char*)d_ws;
  auto alloc = [&](size_t bytes) { char* r = p; p += bytes; return r; };
  u16* embb = (u16*)alloc(8u << 20);
  u16* Wqb  = (u16*)alloc(2u << 20);
  u16* Wkb  = (u16*)alloc(2u << 20);
  u16* Wvb  = (u16*)alloc(2u << 20);
  u16* W0b  = (u16*)alloc(2u << 20);
  u16* W1b  = (u16*)alloc(8u << 20);
  u16* W2b  = (u16*)alloc(8u << 20);
  u16* Qb   = (u16*)alloc(8u << 20);
  u16* Kb   = (u16*)alloc(8u << 20);
  u16* Vb   = (u16*)alloc(8u << 20);
  u16* Zb   = (u16*)alloc(8u << 20);
  float* y1 = (float*)alloc(16u << 20);   // reused as y2 later
  float* o1f = (float*)alloc(16u << 20);
  u16* o1b  = (u16*)alloc(8u << 20);
  u16* hb   = (u16*)alloc(32u << 20);

  auto cvt = [&](const float* s, u16* d, int n) {
    int blk = (n / 4 + 255) / 256;
    if (blk > 4096) blk = 4096;
    k_cvt<<<blk, 256, 0, stream>>>(s, d, n);
  };
  cvt(emb, embb, 4096 * 1024);
  cvt(Wq, Wqb, 1024 * 1024);
  cvt(Wk, Wkb, 1024 * 1024);
  cvt(Wv, Wvb, 1024 * 1024);
  cvt(W0, W0b, 1024 * 1024);
  cvt(W1, W1b, 4096 * 1024);
  cvt(W2, W2b, 4096 * 1024);

  k_gemm_qkv<<<dim3(32, 8, 3), 256, 0, stream>>>(embb, Wqb, Wkb, Wvb, bq, bk, bv,
                                                 Qb, Kb, Vb);
  k_attn<<<dim3(512), 256, 0, stream>>>(Qb, Kb, Vb, Zb);
  // y1 = Z @ W0^T + b0 + emb
  k_gemm<2><<<dim3(32, 8), 256, 0, stream>>>(Zb, W0b, b0, emb, y1, 1024, 1024);
  k_ln<true><<<4096, 256, 0, stream>>>(y1, g1, be1, o1f, o1b);
  // h = relu(out1 @ W1^T + b1)
  k_gemm<1><<<dim3(32, 32), 256, 0, stream>>>(o1b, W1b, b1, nullptr, hb, 4096, 1024);
  // y2 = h @ W2^T + b2 + out1   (reuse y1 buffer)
  k_gemm<2><<<dim3(32, 8), 256, 0, stream>>>(hb, W2b, b2, o1f, y1, 1024, 4096);
  k_ln<false><<<4096, 256, 0, stream>>>(y1, g2, be2, (float*)d_out, nullptr);
}

// Round 5
// 318.376 us; speedup vs baseline: 1.2606x; 1.1083x over previous
//
#include <hip/hip_runtime.h>
#include <hip/hip_bf16.h>
#include <cstdint>
#include <cmath>

#define DEV __device__ __forceinline__

typedef float f32x4 __attribute__((ext_vector_type(4)));
typedef float f32x16 __attribute__((ext_vector_type(16)));
typedef __bf16 bf16x8 __attribute__((ext_vector_type(8)));
typedef unsigned short u16;
typedef u16 u16x8 __attribute__((ext_vector_type(8)));
typedef u16 u16x4 __attribute__((ext_vector_type(4)));

DEV u16 f2bf(float f) {
  union { float f; uint32_t u; } x{f};
  uint32_t r = x.u + 0x7FFFu + ((x.u >> 16) & 1u);
  return (u16)(r >> 16);
}

DEV void gl_lds16(const u16* g, u16* l) {
  __builtin_amdgcn_global_load_lds((const __attribute__((address_space(1))) void*)g,
                                   (__attribute__((address_space(3))) void*)l, 16, 0, 0);
}

// ---------------- f32 -> bf16 convert ----------------
__global__ __launch_bounds__(256) void k_cvt(const float* __restrict__ s,
                                             u16* __restrict__ d, int n) {
  int step = gridDim.x * blockDim.x * 4;
  for (int i = (blockIdx.x * blockDim.x + threadIdx.x) * 4; i < n; i += step) {
    float4 v = *reinterpret_cast<const float4*>(s + i);
    u16x4 o;
    o[0] = f2bf(v.x); o[1] = f2bf(v.y); o[2] = f2bf(v.z); o[3] = f2bf(v.w);
    *reinterpret_cast<u16x4*>(d + i) = o;
  }
}

// 4 same-size converts in one launch (blockIdx.y selects the pair)
__global__ __launch_bounds__(256) void k_cvt4(
    const float* __restrict__ s0, const float* __restrict__ s1,
    const float* __restrict__ s2, const float* __restrict__ s3,
    u16* __restrict__ d0, u16* __restrict__ d1,
    u16* __restrict__ d2, u16* __restrict__ d3, int n) {
  const int y = blockIdx.y;
  const float* s = (y == 0) ? s0 : (y == 1) ? s1 : (y == 2) ? s2 : s3;
  u16* d = (y == 0) ? d0 : (y == 1) ? d1 : (y == 2) ? d2 : d3;
  int step = gridDim.x * blockDim.x * 4;
  for (int i = (blockIdx.x * blockDim.x + threadIdx.x) * 4; i < n; i += step) {
    float4 v = *reinterpret_cast<const float4*>(s + i);
    u16x4 o;
    o[0] = f2bf(v.x); o[1] = f2bf(v.y); o[2] = f2bf(v.z); o[3] = f2bf(v.w);
    *reinterpret_cast<u16x4*>(d + i) = o;
  }
}

// ---------------- GEMM: C[M,N] = A[M,K] @ B[N,K]^T (+bias, epilogue) -------
// MODE 0: bf16 out = (acc+bias)*oscale ; MODE 1: bf16 out = relu(acc+bias)
// MODE 2: f32 out = acc+bias+res
template <int MODE>
DEV void gemm_core(const u16* __restrict__ A, const u16* __restrict__ B,
                   const float* __restrict__ bias, const float* __restrict__ res,
                   void* __restrict__ C, int N, int K, int m0, int n0,
                   float oscale) {
  __shared__ u16 sA[2][128 * 32];
  __shared__ u16 sB[2][128 * 32];
  const int tid = threadIdx.x;
  const int w = tid >> 6, l = tid & 63;
  const int lr = l & 15, lg = l >> 4;
  const int wr = (w >> 1) * 64, wc = (w & 1) * 64;

  f32x4 acc[4][4] = {};

  const int nt = K >> 5;
  const int sr = w * 16 + (l >> 2);  // staging row (within 64-row half)
  const int sc = (l & 3) * 8;        // staging col (elements)

  auto stage = [&](int buf, int t) {
    const u16* ga = A + (size_t)(m0 + sr) * K + t * 32 + sc;
    const u16* gb = B + (size_t)(n0 + sr) * K + t * 32 + sc;
    gl_lds16(ga, &sA[buf][w * 512]);
    gl_lds16(ga + (size_t)64 * K, &sA[buf][2048 + w * 512]);
    gl_lds16(gb, &sB[buf][w * 512]);
    gl_lds16(gb + (size_t)64 * K, &sB[buf][2048 + w * 512]);
  };

  auto compute = [&](int buf) {
    bf16x8 af[4], bfr[4];
#pragma unroll
    for (int mf = 0; mf < 4; ++mf)
      af[mf] = *(const bf16x8*)&sA[buf][(wr + mf * 16 + lr) * 32 + lg * 8];
#pragma unroll
    for (int nf = 0; nf < 4; ++nf)
      bfr[nf] = *(const bf16x8*)&sB[buf][(wc + nf * 16 + lr) * 32 + lg * 8];
#pragma unroll
    for (int mf = 0; mf < 4; ++mf)
#pragma unroll
      for (int nf = 0; nf < 4; ++nf)
        acc[mf][nf] = __builtin_amdgcn_mfma_f32_16x16x32_bf16(af[mf], bfr[nf],
                                                              acc[mf][nf], 0, 0, 0);
  };

  stage(0, 0);
  __syncthreads();
  int cur = 0;
  for (int t = 0; t < nt - 1; ++t) {
    stage(cur ^ 1, t + 1);
    compute(cur);
    __syncthreads();
    cur ^= 1;
  }
  compute(cur);

#pragma unroll
  for (int nf = 0; nf < 4; ++nf) {
    const int col = n0 + wc + nf * 16 + lr;
    const float bv = bias[col];
#pragma unroll
    for (int mf = 0; mf < 4; ++mf) {
      const int row0 = m0 + wr + mf * 16 + lg * 4;
#pragma unroll
      for (int r = 0; r < 4; ++r) {
        float v = acc[mf][nf][r] + bv;
        if (MODE == 0) v *= oscale;
        if (MODE == 1) v = fmaxf(v, 0.0f);
        const size_t idx = (size_t)(row0 + r) * N + col;
        if (MODE == 2) ((float*)C)[idx] = v + res[idx];
        else ((u16*)C)[idx] = f2bf(v);
      }
    }
  }
}

template <int MODE>
__global__ __launch_bounds__(256) void k_gemm(const u16* __restrict__ A,
                                              const u16* __restrict__ B,
                                              const float* __restrict__ bias,
                                              const float* __restrict__ res,
                                              void* __restrict__ C, int N, int K) {
  gemm_core<MODE>(A, B, bias, res, C, N, K, blockIdx.x * 128, blockIdx.y * 128, 1.0f);
}

__global__ __launch_bounds__(256) void k_gemm_qkv(
    const u16* __restrict__ A, const u16* __restrict__ B0, const u16* __restrict__ B1,
    const u16* __restrict__ B2, const float* __restrict__ c0,
    const float* __restrict__ c1, const float* __restrict__ c2,
    u16* __restrict__ O0, u16* __restrict__ O1, u16* __restrict__ O2) {
  const int z = blockIdx.z;
  const u16* B = (z == 0) ? B0 : (z == 1) ? B1 : B2;
  const float* bias = (z == 0) ? c0 : (z == 1) ? c1 : c2;
  u16* O = (z == 0) ? O0 : (z == 1) ? O1 : O2;
  // Q is pre-scaled by log2(e) so attention can use exp2 directly (exact:
  // base change of softmax is a no-op).
  const float sc = (z == 0) ? 1.44269504f : 1.0f;
  gemm_core<0>(A, B, bias, nullptr, O, 1024, 1024, blockIdx.x * 128,
               blockIdx.y * 128, sc);
}

// ---------------- flash attention, swapped 32x32 MFMA, in-register softmax --
// S^T = mfma32(K,Q): lane holds ALL 32 kv-scores of ONE q-row (q = lane&31,
// hi = lane>>5 splits kv). Softmax is lane-local scalars; P->bf16 via
// v_cvt_pk_bf16_f32 + v_permlane32_swap builds PV A-frags in-register (no P
// LDS round-trip). 128 q/block (4 waves x 32), 512 blocks XCD-swizzled,
// K via async global_load_lds (chunk-XOR pre-swizzled source), V^T reg-staged,
// both double-buffered, one barrier per kv-tile.
__global__ __launch_bounds__(256) void k_attn(const u16* __restrict__ Q,
                                              const u16* __restrict__ K,
                                              const u16* __restrict__ V,
                                              u16* __restrict__ Z) {
  const int id = blockIdx.x;
  const int virt = (id & 7) * 64 + (id >> 3);  // 512 = 8 XCD * 64, bijective
  const int bh = virt >> 4;
  const int qt = virt & 15;
  const int b = bh >> 4, h = bh & 15;
  const int tid = threadIdx.x;
  const int w = tid >> 6, l = tid & 63;
  const int q32 = l & 31, hi = l >> 5;

  __shared__ u16 Kl[2][64 * 64];   // K tile, chunk-XOR swizzled (16 KB)
  __shared__ u16 VT[2][64 * 64];   // V^T tile, chunk-XOR swizzled (16 KB)

  const size_t rb = (size_t)b * 2048;
  const int c0 = h * 64;
  const int q0w = qt * 128 + w * 32;

  // Q B-frags: col q=q32, k-elems dh = st*16 + hi*8 + j (8 contiguous)
  bf16x8 qb[4];
#pragma unroll
  for (int st = 0; st < 4; ++st)
    qb[st] = *(const bf16x8*)(Q + (rb + q0w + q32) * 1024 + c0 + st * 16 + hi * 8);

  f32x16 zacc[2] = {};
  float mrun = -1e30f, lrun = 0.f;

  // K staging: wave w stages kv rows 16w..16w+15; LDS[kv][chunk c] holds
  // global dh-chunk (c ^ (kv&7)) -> strided b128 reads are conflict-free.
  const int skv = w * 16 + (l >> 3);
  const int sc8 = l & 7;
  auto stage_k = [&](int pp, int t) {
#pragma unroll
    for (int cq = 0; cq < 2; ++cq) {
      const int kvl = skv + cq * 8;
      const int dh0 = (sc8 ^ (kvl & 7)) * 8;
      gl_lds16(K + (rb + t * 64 + kvl) * 1024 + c0 + dh0,
               &Kl[pp][w * 1024 + cq * 512]);
    }
  };

  // V: global -> regs (issue-early), regs -> swizzled VT (write-late)
  const int vp = tid & 31, vd0 = (tid >> 5) * 8;
  u16x8 va0, va1;
  auto vload = [&](int t) {
    const u16* v0 = V + (rb + t * 64 + 2 * vp) * 1024 + c0 + vd0;
    va0 = *(const u16x8*)v0;
    va1 = *(const u16x8*)(v0 + 1024);
  };
  auto vstore = [&](int pp) {
#pragma unroll
    for (int i = 0; i < 8; ++i) {
      const int dh = vd0 + i;
      const int off = ((2 * vp) & 7) + 8 * ((vp >> 2) ^ (dh & 7));
      uint32_t pk = (uint32_t)va0[i] | ((uint32_t)va1[i] << 16);
      *(uint32_t*)&VT[pp][dh * 64 + off] = pk;
    }
  };

  stage_k(0, 0);
  vload(0);
  vstore(0);
  __syncthreads();

  for (int t = 0; t < 32; ++t) {
    const int p = t & 1;
    if (t + 1 < 32) {
      stage_k(p ^ 1, t + 1);  // async into idle buffer
      vload(t + 1);           // latency hides under QK+softmax
    }
    // QK^T swapped: s[nf] rows = kv (32nf + cr(r,hi)), cols = q (lane&31)
    f32x16 s[2] = {};
    __builtin_amdgcn_s_setprio(1);
#pragma unroll
    for (int nf = 0; nf < 2; ++nf)
#pragma unroll
      for (int st = 0; st < 4; ++st) {
        bf16x8 ka = *(const bf16x8*)&Kl[p][(nf * 32 + q32) * 64 +
                                           ((st * 2 + hi) ^ (q32 & 7)) * 8];
        s[nf] = __builtin_amdgcn_mfma_f32_32x32x16_bf16(ka, qb[st], s[nf], 0, 0, 0);
      }
    __builtin_amdgcn_s_setprio(0);

    // lane-local row max (32 values) + one cross-hi exchange
    float m = s[0][0];
#pragma unroll
    for (int r = 1; r < 16; ++r) m = fmaxf(m, s[0][r]);
#pragma unroll
    for (int r = 0; r < 16; ++r) m = fmaxf(m, s[1][r]);
    m = fmaxf(m, __shfl_xor(m, 32, 64));

    // defer-max (THR=8 log2 units -> P <= 256, fine in bf16)
    if (__any(m > mrun + 8.0f)) {
      float mn = fmaxf(mrun, m);
      float sc = exp2f(mrun - mn);
      mrun = mn;
      lrun *= sc;
#pragma unroll
      for (int r = 0; r < 16; ++r) {
        float scr = __shfl(sc, (r & 3) + 8 * (r >> 2) + 4 * hi, 64);
        zacc[0][r] *= scr;
        zacc[1][r] *= scr;
      }
    }

    // exp2 + pack pairs to bf16 (c[nf*8+m2] = kv pair (cr(2m2),cr(2m2)+1))
    uint32_t c[16];
#pragma unroll
    for (int nf = 0; nf < 2; ++nf)
#pragma unroll
      for (int m2 = 0; m2 < 8; ++m2) {
        float p0 = exp2f(s[nf][2 * m2] - mrun);
        float p1 = exp2f(s[nf][2 * m2 + 1] - mrun);
        lrun += p0 + p1;
        uint32_t pk;
        asm("v_cvt_pk_bf16_f32 %0, %1, %2" : "=v"(pk) : "v"(p0), "v"(p1));
        c[nf * 8 + m2] = pk;
      }
    // cross-hi exchange: after swaps, c[4ks..4ks+3] IS the PV A-frag for
    // kv-slice ks (row q = lane&31, k = 16ks + 8hi + j)
#pragma unroll
    for (int ks = 0; ks < 4; ++ks) {
      asm("v_permlane32_swap_b32 %0, %1" : "+v"(c[4 * ks]), "+v"(c[4 * ks + 2]));
      asm("v_permlane32_swap_b32 %0, %1" : "+v"(c[4 * ks + 1]), "+v"(c[4 * ks + 3]));
    }

    if (t + 1 < 32) vstore(p ^ 1);  // VT writes overlap with PV

    // PV: Z = P*V ; A = P-frag (in regs), B = V^T-frag from VT
    __builtin_amdgcn_s_setprio(1);
#pragma unroll
    for (int ks = 0; ks < 4; ++ks) {
      union { uint32_t u[4]; bf16x8 v; } pa;
#pragma unroll
      for (int i = 0; i < 4; ++i) pa.u[i] = c[4 * ks + i];
#pragma unroll
      for (int nd = 0; nd < 2; ++nd) {
        bf16x8 vb = *(const bf16x8*)&VT[p][(nd * 32 + q32) * 64 +
                                           ((ks * 2 + hi) ^ (q32 & 7)) * 8];
        zacc[nd] = __builtin_amdgcn_mfma_f32_32x32x16_bf16(pa.v, vb, zacc[nd], 0, 0, 0);
      }
    }
    __builtin_amdgcn_s_setprio(0);
    __syncthreads();  // next K (vmcnt) + VT ready; protects buffer reuse
  }

  // denominator: lane holds half the kv-sum for its q; other half at lane^32
  float ltot = lrun + __shfl_xor(lrun, 32, 64);
  float inv = 0.125f / ltot;  // /sqrt(64) folded in
#pragma unroll
  for (int r = 0; r < 16; ++r) {
    float invr = __shfl(inv, (r & 3) + 8 * (r >> 2) + 4 * hi, 64);
    const size_t row = rb + q0w + (r & 3) + 8 * (r >> 2) + 4 * hi;
#pragma unroll
    for (int nd = 0; nd < 2; ++nd)
      Z[row * 1024 + c0 + nd * 32 + q32] = f2bf(zacc[nd][r] * invr);
  }
}

// ---------------- row LayerNorm (1024 cols) ----------------
template <bool WBF>
__global__ __launch_bounds__(256) void k_ln(const float* __restrict__ x,
                                            const float* __restrict__ g,
                                            const float* __restrict__ be,
                                            float* __restrict__ of,
                                            u16* __restrict__ ob) {
  const int row = blockIdx.x;
  const int tid = threadIdx.x;
  const float* xr = x + (size_t)row * 1024;
  float4 v = *(const float4*)(xr + tid * 4);
  float s = v.x + v.y + v.z + v.w;
  float s2 = v.x * v.x + v.y * v.y + v.z * v.z + v.w * v.w;
#pragma unroll
  for (int st = 1; st < 64; st <<= 1) {
    s += __shfl_xor(s, st, 64);
    s2 += __shfl_xor(s2, st, 64);
  }
  __shared__ float ps[8];
  if ((tid & 63) == 0) { ps[tid >> 6] = s; ps[4 + (tid >> 6)] = s2; }
  __syncthreads();
  s = ps[0] + ps[1] + ps[2] + ps[3];
  s2 = ps[4] + ps[5] + ps[6] + ps[7];
  const float mu = s * 0.0009765625f;
  const float var = s2 * 0.0009765625f - mu * mu;
  const float rs = rsqrtf(var + 1e-5f);
  float4 gg = *(const float4*)(g + tid * 4);
  float4 bb = *(const float4*)(be + tid * 4);
  float4 o;
  o.x = (v.x - mu) * rs * gg.x + bb.x;
  o.y = (v.y - mu) * rs * gg.y + bb.y;
  o.z = (v.z - mu) * rs * gg.z + bb.z;
  o.w = (v.w - mu) * rs * gg.w + bb.w;
  *(float4*)(of + (size_t)row * 1024 + tid * 4) = o;
  if (WBF) {
    u16x4 q;
    q[0] = f2bf(o.x); q[1] = f2bf(o.y); q[2] = f2bf(o.z); q[3] = f2bf(o.w);
    *(u16x4*)(ob + (size_t)row * 1024 + tid * 4) = q;
  }
}

// ---------------- launch ----------------
extern "C" void kernel_launch(void* const* d_in, const int* in_sizes, int n_in,
                              void* d_out, int out_size, void* d_ws, size_t ws_size,
                              hipStream_t stream) {
  const float* emb = (const float*)d_in[0];
  const float* Wq  = (const float*)d_in[1];
  const float* bq  = (const float*)d_in[2];
  const float* Wk  = (const float*)d_in[3];
  const float* bk  = (const float*)d_in[4];
  const float* Wv  = (const float*)d_in[5];
  const float* bv  = (const float*)d_in[6];
  const float* W0  = (const float*)d_in[7];
  const float* b0  = (const float*)d_in[8];
  const float* g1  = (const float*)d_in[9];
  const float* be1 = (const float*)d_in[10];
  const float* W1  = (const float*)d_in[11];
  const float* b1  = (const float*)d_in[12];
  const float* W2  = (const float*)d_in[13];
  const float* b2  = (const float*)d_in[14];
  const float* g2  = (const float*)d_in[15];
  const float* be2 = (const float*)d_in[16];

  char* p = (char*)d_ws;
  auto alloc = [&](size_t bytes) { char* r = p; p += bytes; return r; };
  u16* embb = (u16*)alloc(8u << 20);
  u16* Wqb  = (u16*)alloc(2u << 20);
  u16* Wkb  = (u16*)alloc(2u << 20);
  u16* Wvb  = (u16*)alloc(2u << 20);
  u16* W0b  = (u16*)alloc(2u << 20);
  u16* W1b  = (u16*)alloc(8u << 20);
  u16* W2b  = (u16*)alloc(8u << 20);
  u16* Qb   = (u16*)alloc(8u << 20);
  u16* Kb   = (u16*)alloc(8u << 20);
  u16* Vb   = (u16*)alloc(8u << 20);
  u16* Zb   = (u16*)alloc(8u << 20);
  float* y1 = (float*)alloc(16u << 20);   // reused as y2 later
  float* o1f = (float*)alloc(16u << 20);
  u16* o1b  = (u16*)alloc(8u << 20);
  u16* hb   = (u16*)alloc(32u << 20);

  auto cvt = [&](const float* s, u16* d, int n) {
    int blk = (n / 4 + 255) / 256;
    if (blk > 4096) blk = 4096;
    k_cvt<<<blk, 256, 0, stream>>>(s, d, n);
  };
  cvt(emb, embb, 4096 * 1024);
  k_cvt4<<<dim3(1024, 4), 256, 0, stream>>>(Wq, Wk, Wv, W0, Wqb, Wkb, Wvb, W0b,
                                            1024 * 1024);
  cvt(W1, W1b, 4096 * 1024);
  cvt(W2, W2b, 4096 * 1024);

  k_gemm_qkv<<<dim3(32, 8, 3), 256, 0, stream>>>(embb, Wqb, Wkb, Wvb, bq, bk, bv,
                                                 Qb, Kb, Vb);
  k_attn<<<dim3(512), 256, 0, stream>>>(Qb, Kb, Vb, Zb);
  // y1 = Z @ W0^T + b0 + emb
  k_gemm<2><<<dim3(32, 8), 256, 0, stream>>>(Zb, W0b, b0, emb, y1, 1024, 1024);
  k_ln<true><<<4096, 256, 0, stream>>>(y1, g1, be1, o1f, o1b);
  // h = relu(out1 @ W1^T + b1)
  k_gemm<1><<<dim3(32, 32), 256, 0, stream>>>(o1b, W1b, b1, nullptr, hb, 4096, 1024);
  // y2 = h @ W2^T + b2 + out1   (reuse y1 buffer)
  k_gemm<2><<<dim3(32, 8), 256, 0, stream>>>(hb, W2b, b2, o1f, y1, 1024, 4096);
  k_ln<false><<<4096, 256, 0, stream>>>(y1, g2, be2, (float*)d_out, nullptr);
}

// Round 6
// 312.224 us; speedup vs baseline: 1.2855x; 1.0197x over previous
//
#include <hip/hip_runtime.h>
#include <hip/hip_bf16.h>
#include <cstdint>
#include <cmath>

#define DEV __device__ __forceinline__

typedef float f32x4 __attribute__((ext_vector_type(4)));
typedef float f32x16 __attribute__((ext_vector_type(16)));
typedef __bf16 bf16x8 __attribute__((ext_vector_type(8)));
typedef unsigned short u16;
typedef u16 u16x8 __attribute__((ext_vector_type(8)));
typedef u16 u16x4 __attribute__((ext_vector_type(4)));

DEV u16 f2bf(float f) {
  union { float f; uint32_t u; } x{f};
  uint32_t r = x.u + 0x7FFFu + ((x.u >> 16) & 1u);
  return (u16)(r >> 16);
}

DEV void gl_lds16(const u16* g, u16* l) {
  __builtin_amdgcn_global_load_lds((const __attribute__((address_space(1))) void*)g,
                                   (__attribute__((address_space(3))) void*)l, 16, 0, 0);
}

// ---------------- f32 -> bf16 convert ----------------
__global__ __launch_bounds__(256) void k_cvt(const float* __restrict__ s,
                                             u16* __restrict__ d, int n) {
  int step = gridDim.x * blockDim.x * 4;
  for (int i = (blockIdx.x * blockDim.x + threadIdx.x) * 4; i < n; i += step) {
    float4 v = *reinterpret_cast<const float4*>(s + i);
    u16x4 o;
    o[0] = f2bf(v.x); o[1] = f2bf(v.y); o[2] = f2bf(v.z); o[3] = f2bf(v.w);
    *reinterpret_cast<u16x4*>(d + i) = o;
  }
}

// 4 same-size converts in one launch (blockIdx.y selects the pair)
__global__ __launch_bounds__(256) void k_cvt4(
    const float* __restrict__ s0, const float* __restrict__ s1,
    const float* __restrict__ s2, const float* __restrict__ s3,
    u16* __restrict__ d0, u16* __restrict__ d1,
    u16* __restrict__ d2, u16* __restrict__ d3, int n) {
  const int y = blockIdx.y;
  const float* s = (y == 0) ? s0 : (y == 1) ? s1 : (y == 2) ? s2 : s3;
  u16* d = (y == 0) ? d0 : (y == 1) ? d1 : (y == 2) ? d2 : d3;
  int step = gridDim.x * blockDim.x * 4;
  for (int i = (blockIdx.x * blockDim.x + threadIdx.x) * 4; i < n; i += step) {
    float4 v = *reinterpret_cast<const float4*>(s + i);
    u16x4 o;
    o[0] = f2bf(v.x); o[1] = f2bf(v.y); o[2] = f2bf(v.z); o[3] = f2bf(v.w);
    *reinterpret_cast<u16x4*>(d + i) = o;
  }
}

// ---------------- GEMM cores: C[M,N] = A[M,K] @ B[N,K]^T (+bias, epilogue) --
// MODE 0: bf16 out = (acc+bias)*oscale ; MODE 1: bf16 out = relu(acc+bias)
// MODE 2: f32 out = acc+bias+res

// 128x128 tile, 4 waves (2x2 of 64x64), LDS 32 KB.
template <int MODE>
DEV void gemm_core128(const u16* __restrict__ A, const u16* __restrict__ B,
                      const float* __restrict__ bias, const float* __restrict__ res,
                      void* __restrict__ C, int N, int K, int m0, int n0,
                      float oscale) {
  __shared__ u16 sA[2][128 * 32];
  __shared__ u16 sB[2][128 * 32];
  const int tid = threadIdx.x;
  const int w = tid >> 6, l = tid & 63;
  const int lr = l & 15, lg = l >> 4;
  const int wr = (w >> 1) * 64, wc = (w & 1) * 64;

  f32x4 acc[4][4] = {};

  const int nt = K >> 5;
  const int sr = w * 16 + (l >> 2);
  const int sc = (l & 3) * 8;

  auto stage = [&](int buf, int t) {
    const u16* ga = A + (size_t)(m0 + sr) * K + t * 32 + sc;
    const u16* gb = B + (size_t)(n0 + sr) * K + t * 32 + sc;
    gl_lds16(ga, &sA[buf][w * 512]);
    gl_lds16(ga + (size_t)64 * K, &sA[buf][2048 + w * 512]);
    gl_lds16(gb, &sB[buf][w * 512]);
    gl_lds16(gb + (size_t)64 * K, &sB[buf][2048 + w * 512]);
  };

  auto compute = [&](int buf) {
    bf16x8 af[4], bfr[4];
#pragma unroll
    for (int mf = 0; mf < 4; ++mf)
      af[mf] = *(const bf16x8*)&sA[buf][(wr + mf * 16 + lr) * 32 + lg * 8];
#pragma unroll
    for (int nf = 0; nf < 4; ++nf)
      bfr[nf] = *(const bf16x8*)&sB[buf][(wc + nf * 16 + lr) * 32 + lg * 8];
#pragma unroll
    for (int mf = 0; mf < 4; ++mf)
#pragma unroll
      for (int nf = 0; nf < 4; ++nf)
        acc[mf][nf] = __builtin_amdgcn_mfma_f32_16x16x32_bf16(af[mf], bfr[nf],
                                                              acc[mf][nf], 0, 0, 0);
  };

  stage(0, 0);
  __syncthreads();
  int cur = 0;
  for (int t = 0; t < nt - 1; ++t) {
    stage(cur ^ 1, t + 1);
    compute(cur);
    __syncthreads();
    cur ^= 1;
  }
  compute(cur);

#pragma unroll
  for (int nf = 0; nf < 4; ++nf) {
    const int col = n0 + wc + nf * 16 + lr;
    const float bv = bias[col];
#pragma unroll
    for (int mf = 0; mf < 4; ++mf) {
      const int row0 = m0 + wr + mf * 16 + lg * 4;
#pragma unroll
      for (int r = 0; r < 4; ++r) {
        float v = acc[mf][nf][r] + bv;
        if (MODE == 0) v *= oscale;
        if (MODE == 1) v = fmaxf(v, 0.0f);
        const size_t idx = (size_t)(row0 + r) * N + col;
        if (MODE == 2) ((float*)C)[idx] = v + res[idx];
        else ((u16*)C)[idx] = f2bf(v);
      }
    }
  }
}

// 64x128 tile, 4 waves (2x2 of 32x64), LDS 24 KB. For N=1024 GEMMs where a
// 128-row tile leaves the grid at 1 block/CU (latency-bound, round-5 PMC).
template <int MODE>
DEV void gemm_core64(const u16* __restrict__ A, const u16* __restrict__ B,
                     const float* __restrict__ bias, const float* __restrict__ res,
                     void* __restrict__ C, int N, int K, int m0, int n0,
                     float oscale) {
  __shared__ u16 sA[2][64 * 32];
  __shared__ u16 sB[2][128 * 32];
  const int tid = threadIdx.x;
  const int w = tid >> 6, l = tid & 63;
  const int lr = l & 15, lg = l >> 4;
  const int wr = (w >> 1) * 32, wc = (w & 1) * 64;

  f32x4 acc[2][4] = {};

  const int nt = K >> 5;
  const int sr = w * 16 + (l >> 2);  // 0..63 across the block
  const int sc = (l & 3) * 8;

  auto stage = [&](int buf, int t) {
    // A: one 16B op per lane stages the whole 64x32 tile (wave w -> rows 16w..)
    gl_lds16(A + (size_t)(m0 + sr) * K + t * 32 + sc, &sA[buf][w * 512]);
    const u16* gb = B + (size_t)(n0 + sr) * K + t * 32 + sc;
    gl_lds16(gb, &sB[buf][w * 512]);
    gl_lds16(gb + (size_t)64 * K, &sB[buf][2048 + w * 512]);
  };

  auto compute = [&](int buf) {
    bf16x8 af[2], bfr[4];
#pragma unroll
    for (int mf = 0; mf < 2; ++mf)
      af[mf] = *(const bf16x8*)&sA[buf][(wr + mf * 16 + lr) * 32 + lg * 8];
#pragma unroll
    for (int nf = 0; nf < 4; ++nf)
      bfr[nf] = *(const bf16x8*)&sB[buf][(wc + nf * 16 + lr) * 32 + lg * 8];
#pragma unroll
    for (int mf = 0; mf < 2; ++mf)
#pragma unroll
      for (int nf = 0; nf < 4; ++nf)
        acc[mf][nf] = __builtin_amdgcn_mfma_f32_16x16x32_bf16(af[mf], bfr[nf],
                                                              acc[mf][nf], 0, 0, 0);
  };

  stage(0, 0);
  __syncthreads();
  int cur = 0;
  for (int t = 0; t < nt - 1; ++t) {
    stage(cur ^ 1, t + 1);
    compute(cur);
    __syncthreads();
    cur ^= 1;
  }
  compute(cur);

#pragma unroll
  for (int nf = 0; nf < 4; ++nf) {
    const int col = n0 + wc + nf * 16 + lr;
    const float bv = bias[col];
#pragma unroll
    for (int mf = 0; mf < 2; ++mf) {
      const int row0 = m0 + wr + mf * 16 + lg * 4;
#pragma unroll
      for (int r = 0; r < 4; ++r) {
        float v = acc[mf][nf][r] + bv;
        if (MODE == 0) v *= oscale;
        if (MODE == 1) v = fmaxf(v, 0.0f);
        const size_t idx = (size_t)(row0 + r) * N + col;
        if (MODE == 2) ((float*)C)[idx] = v + res[idx];
        else ((u16*)C)[idx] = f2bf(v);
      }
    }
  }
}

template <int MODE>
__global__ __launch_bounds__(256) void k_gemm(const u16* __restrict__ A,
                                              const u16* __restrict__ B,
                                              const float* __restrict__ bias,
                                              const float* __restrict__ res,
                                              void* __restrict__ C, int N, int K) {
  gemm_core128<MODE>(A, B, bias, res, C, N, K, blockIdx.x * 128, blockIdx.y * 128, 1.0f);
}

template <int MODE>
__global__ __launch_bounds__(256) void k_gemm64(const u16* __restrict__ A,
                                                const u16* __restrict__ B,
                                                const float* __restrict__ bias,
                                                const float* __restrict__ res,
                                                void* __restrict__ C, int N, int K) {
  gemm_core64<MODE>(A, B, bias, res, C, N, K, blockIdx.x * 64, blockIdx.y * 128, 1.0f);
}

__global__ __launch_bounds__(256) void k_gemm_qkv(
    const u16* __restrict__ A, const u16* __restrict__ B0, const u16* __restrict__ B1,
    const u16* __restrict__ B2, const float* __restrict__ c0,
    const float* __restrict__ c1, const float* __restrict__ c2,
    u16* __restrict__ O0, u16* __restrict__ O1, u16* __restrict__ O2) {
  const int z = blockIdx.z;
  const u16* B = (z == 0) ? B0 : (z == 1) ? B1 : B2;
  const float* bias = (z == 0) ? c0 : (z == 1) ? c1 : c2;
  u16* O = (z == 0) ? O0 : (z == 1) ? O1 : O2;
  // Q pre-scaled by log2(e) so attention can run softmax in exp2 domain.
  const float sc = (z == 0) ? 1.44269504f : 1.0f;
  gemm_core64<0>(A, B, bias, nullptr, O, 1024, 1024, blockIdx.x * 64,
                 blockIdx.y * 128, sc);
}

// ---------------- flash attention, swapped 32x32 MFMA, in-register softmax --
// S^T = mfma32(K,Q): lane holds ALL 32 kv-scores of ONE q-row (q = lane&31,
// hi = lane>>5 splits kv). Softmax is lane-local scalars; P->bf16 via
// v_cvt_pk_bf16_f32 + v_permlane32_swap builds PV A-frags in-register (no P
// LDS round-trip). 128 q/block (4 waves x 32), 512 blocks XCD-swizzled,
// K via async global_load_lds (chunk-XOR pre-swizzled source), V^T reg-staged,
// both double-buffered, one barrier per kv-tile.
__global__ __launch_bounds__(256) void k_attn(const u16* __restrict__ Q,
                                              const u16* __restrict__ K,
                                              const u16* __restrict__ V,
                                              u16* __restrict__ Z) {
  const int id = blockIdx.x;
  const int virt = (id & 7) * 64 + (id >> 3);  // 512 = 8 XCD * 64, bijective
  const int bh = virt >> 4;
  const int qt = virt & 15;
  const int b = bh >> 4, h = bh & 15;
  const int tid = threadIdx.x;
  const int w = tid >> 6, l = tid & 63;
  const int q32 = l & 31, hi = l >> 5;

  __shared__ u16 Kl[2][64 * 64];   // K tile, chunk-XOR swizzled (16 KB)
  __shared__ u16 VT[2][64 * 64];   // V^T tile, chunk-XOR swizzled (16 KB)

  const size_t rb = (size_t)b * 2048;
  const int c0 = h * 64;
  const int q0w = qt * 128 + w * 32;

  // Q B-frags: col q=q32, k-elems dh = st*16 + hi*8 + j (8 contiguous)
  bf16x8 qb[4];
#pragma unroll
  for (int st = 0; st < 4; ++st)
    qb[st] = *(const bf16x8*)(Q + (rb + q0w + q32) * 1024 + c0 + st * 16 + hi * 8);

  f32x16 zacc[2] = {};
  float mrun = -1e30f, lrun = 0.f;

  // K staging: wave w stages kv rows 16w..16w+15; LDS[kv][chunk c] holds
  // global dh-chunk (c ^ (kv&7)) -> strided b128 reads are conflict-free.
  const int skv = w * 16 + (l >> 3);
  const int sc8 = l & 7;
  auto stage_k = [&](int pp, int t) {
#pragma unroll
    for (int cq = 0; cq < 2; ++cq) {
      const int kvl = skv + cq * 8;
      const int dh0 = (sc8 ^ (kvl & 7)) * 8;
      gl_lds16(K + (rb + t * 64 + kvl) * 1024 + c0 + dh0,
               &Kl[pp][w * 1024 + cq * 512]);
    }
  };

  // V: global -> regs (issue-early), regs -> swizzled VT (write-late)
  const int vp = tid & 31, vd0 = (tid >> 5) * 8;
  u16x8 va0, va1;
  auto vload = [&](int t) {
    const u16* v0 = V + (rb + t * 64 + 2 * vp) * 1024 + c0 + vd0;
    va0 = *(const u16x8*)v0;
    va1 = *(const u16x8*)(v0 + 1024);
  };
  auto vstore = [&](int pp) {
#pragma unroll
    for (int i = 0; i < 8; ++i) {
      const int dh = vd0 + i;
      const int off = ((2 * vp) & 7) + 8 * ((vp >> 2) ^ (dh & 7));
      uint32_t pk = (uint32_t)va0[i] | ((uint32_t)va1[i] << 16);
      *(uint32_t*)&VT[pp][dh * 64 + off] = pk;
    }
  };

  stage_k(0, 0);
  vload(0);
  vstore(0);
  __syncthreads();

  for (int t = 0; t < 32; ++t) {
    const int p = t & 1;
    if (t + 1 < 32) {
      stage_k(p ^ 1, t + 1);  // async into idle buffer
      vload(t + 1);           // latency hides under QK+softmax
    }
    // QK^T swapped: s[nf] rows = kv (32nf + cr(r,hi)), cols = q (lane&31)
    f32x16 s[2] = {};
    __builtin_amdgcn_s_setprio(1);
#pragma unroll
    for (int nf = 0; nf < 2; ++nf)
#pragma unroll
      for (int st = 0; st < 4; ++st) {
        bf16x8 ka = *(const bf16x8*)&Kl[p][(nf * 32 + q32) * 64 +
                                           ((st * 2 + hi) ^ (q32 & 7)) * 8];
        s[nf] = __builtin_amdgcn_mfma_f32_32x32x16_bf16(ka, qb[st], s[nf], 0, 0, 0);
      }
    __builtin_amdgcn_s_setprio(0);

    // lane-local row max (32 values) + one cross-hi exchange
    float m = s[0][0];
#pragma unroll
    for (int r = 1; r < 16; ++r) m = fmaxf(m, s[0][r]);
#pragma unroll
    for (int r = 0; r < 16; ++r) m = fmaxf(m, s[1][r]);
    m = fmaxf(m, __shfl_xor(m, 32, 64));

    // defer-max (THR=8 log2 units -> P <= 256, fine in bf16)
    if (__any(m > mrun + 8.0f)) {
      float mn = fmaxf(mrun, m);
      float sc = exp2f(mrun - mn);
      mrun = mn;
      lrun *= sc;
#pragma unroll
      for (int r = 0; r < 16; ++r) {
        float scr = __shfl(sc, (r & 3) + 8 * (r >> 2) + 4 * hi, 64);
        zacc[0][r] *= scr;
        zacc[1][r] *= scr;
      }
    }

    // exp2 + pack pairs to bf16 (c[nf*8+m2] = kv pair (cr(2m2),cr(2m2)+1))
    uint32_t c[16];
#pragma unroll
    for (int nf = 0; nf < 2; ++nf)
#pragma unroll
      for (int m2 = 0; m2 < 8; ++m2) {
        float p0 = exp2f(s[nf][2 * m2] - mrun);
        float p1 = exp2f(s[nf][2 * m2 + 1] - mrun);
        lrun += p0 + p1;
        uint32_t pk;
        asm("v_cvt_pk_bf16_f32 %0, %1, %2" : "=v"(pk) : "v"(p0), "v"(p1));
        c[nf * 8 + m2] = pk;
      }
    // cross-hi exchange: after swaps, c[4ks..4ks+3] IS the PV A-frag for
    // kv-slice ks (row q = lane&31, k = 16ks + 8hi + j)
#pragma unroll
    for (int ks = 0; ks < 4; ++ks) {
      asm("v_permlane32_swap_b32 %0, %1" : "+v"(c[4 * ks]), "+v"(c[4 * ks + 2]));
      asm("v_permlane32_swap_b32 %0, %1" : "+v"(c[4 * ks + 1]), "+v"(c[4 * ks + 3]));
    }

    if (t + 1 < 32) vstore(p ^ 1);  // VT writes overlap with PV

    // PV: Z = P*V ; A = P-frag (in regs), B = V^T-frag from VT
    __builtin_amdgcn_s_setprio(1);
#pragma unroll
    for (int ks = 0; ks < 4; ++ks) {
      union { uint32_t u[4]; bf16x8 v; } pa;
#pragma unroll
      for (int i = 0; i < 4; ++i) pa.u[i] = c[4 * ks + i];
#pragma unroll
      for (int nd = 0; nd < 2; ++nd) {
        bf16x8 vb = *(const bf16x8*)&VT[p][(nd * 32 + q32) * 64 +
                                           ((ks * 2 + hi) ^ (q32 & 7)) * 8];
        zacc[nd] = __builtin_amdgcn_mfma_f32_32x32x16_bf16(pa.v, vb, zacc[nd], 0, 0, 0);
      }
    }
    __builtin_amdgcn_s_setprio(0);
    __syncthreads();  // next K (vmcnt) + VT ready; protects buffer reuse
  }

  // denominator: lane holds half the kv-sum for its q; other half at lane^32
  float ltot = lrun + __shfl_xor(lrun, 32, 64);
  float inv = 0.125f / ltot;  // /sqrt(64) folded in
#pragma unroll
  for (int r = 0; r < 16; ++r) {
    float invr = __shfl(inv, (r & 3) + 8 * (r >> 2) + 4 * hi, 64);
    const size_t row = rb + q0w + (r & 3) + 8 * (r >> 2) + 4 * hi;
#pragma unroll
    for (int nd = 0; nd < 2; ++nd)
      Z[row * 1024 + c0 + nd * 32 + q32] = f2bf(zacc[nd][r] * invr);
  }
}

// ---------------- row LayerNorm (1024 cols) ----------------
template <bool WBF>
__global__ __launch_bounds__(256) void k_ln(const float* __restrict__ x,
                                            const float* __restrict__ g,
                                            const float* __restrict__ be,
                                            float* __restrict__ of,
                                            u16* __restrict__ ob) {
  const int row = blockIdx.x;
  const int tid = threadIdx.x;
  const float* xr = x + (size_t)row * 1024;
  float4 v = *(const float4*)(xr + tid * 4);
  float s = v.x + v.y + v.z + v.w;
  float s2 = v.x * v.x + v.y * v.y + v.z * v.z + v.w * v.w;
#pragma unroll
  for (int st = 1; st < 64; st <<= 1) {
    s += __shfl_xor(s, st, 64);
    s2 += __shfl_xor(s2, st, 64);
  }
  __shared__ float ps[8];
  if ((tid & 63) == 0) { ps[tid >> 6] = s; ps[4 + (tid >> 6)] = s2; }
  __syncthreads();
  s = ps[0] + ps[1] + ps[2] + ps[3];
  s2 = ps[4] + ps[5] + ps[6] + ps[7];
  const float mu = s * 0.0009765625f;
  const float var = s2 * 0.0009765625f - mu * mu;
  const float rs = rsqrtf(var + 1e-5f);
  float4 gg = *(const float4*)(g + tid * 4);
  float4 bb = *(const float4*)(be + tid * 4);
  float4 o;
  o.x = (v.x - mu) * rs * gg.x + bb.x;
  o.y = (v.y - mu) * rs * gg.y + bb.y;
  o.z = (v.z - mu) * rs * gg.z + bb.z;
  o.w = (v.w - mu) * rs * gg.w + bb.w;
  *(float4*)(of + (size_t)row * 1024 + tid * 4) = o;
  if (WBF) {
    u16x4 q;
    q[0] = f2bf(o.x); q[1] = f2bf(o.y); q[2] = f2bf(o.z); q[3] = f2bf(o.w);
    *(u16x4*)(ob + (size_t)row * 1024 + tid * 4) = q;
  }
}

// ---------------- launch ----------------
extern "C" void kernel_launch(void* const* d_in, const int* in_sizes, int n_in,
                              void* d_out, int out_size, void* d_ws, size_t ws_size,
                              hipStream_t stream) {
  const float* emb = (const float*)d_in[0];
  const float* Wq  = (const float*)d_in[1];
  const float* bq  = (const float*)d_in[2];
  const float* Wk  = (const float*)d_in[3];
  const float* bk  = (const float*)d_in[4];
  const float* Wv  = (const float*)d_in[5];
  const float* bv  = (const float*)d_in[6];
  const float* W0  = (const float*)d_in[7];
  const float* b0  = (const float*)d_in[8];
  const float* g1  = (const float*)d_in[9];
  const float* be1 = (const float*)d_in[10];
  const float* W1  = (const float*)d_in[11];
  const float* b1  = (const float*)d_in[12];
  const float* W2  = (const float*)d_in[13];
  const float* b2  = (const float*)d_in[14];
  const float* g2  = (const float*)d_in[15];
  const float* be2 = (const float*)d_in[16];

  char* p = (char*)d_ws;
  auto alloc = [&](size_t bytes) { char* r = p; p += bytes; return r; };
  u16* embb = (u16*)alloc(8u << 20);
  u16* Wqb  = (u16*)alloc(2u << 20);
  u16* Wkb  = (u16*)alloc(2u << 20);
  u16* Wvb  = (u16*)alloc(2u << 20);
  u16* W0b  = (u16*)alloc(2u << 20);
  u16* W1b  = (u16*)alloc(8u << 20);
  u16* W2b  = (u16*)alloc(8u << 20);
  u16* Qb   = (u16*)alloc(8u << 20);
  u16* Kb   = (u16*)alloc(8u << 20);
  u16* Vb   = (u16*)alloc(8u << 20);
  u16* Zb   = (u16*)alloc(8u << 20);
  float* y1 = (float*)alloc(16u << 20);   // reused as y2 later
  float* o1f = (float*)alloc(16u << 20);
  u16* o1b  = (u16*)alloc(8u << 20);
  u16* hb   = (u16*)alloc(32u << 20);

  auto cvt = [&](const float* s, u16* d, int n) {
    int blk = (n / 4 + 255) / 256;
    if (blk > 4096) blk = 4096;
    k_cvt<<<blk, 256, 0, stream>>>(s, d, n);
  };
  cvt(emb, embb, 4096 * 1024);
  k_cvt4<<<dim3(1024, 4), 256, 0, stream>>>(Wq, Wk, Wv, W0, Wqb, Wkb, Wvb, W0b,
                                            1024 * 1024);
  cvt(W1, W1b, 4096 * 1024);
  cvt(W2, W2b, 4096 * 1024);

  k_gemm_qkv<<<dim3(64, 8, 3), 256, 0, stream>>>(embb, Wqb, Wkb, Wvb, bq, bk, bv,
                                                 Qb, Kb, Vb);
  k_attn<<<dim3(512), 256, 0, stream>>>(Qb, Kb, Vb, Zb);
  // y1 = Z @ W0^T + b0 + emb
  k_gemm64<2><<<dim3(64, 8), 256, 0, stream>>>(Zb, W0b, b0, emb, y1, 1024, 1024);
  k_ln<true><<<4096, 256, 0, stream>>>(y1, g1, be1, o1f, o1b);
  // h = relu(out1 @ W1^T + b1)
  k_gemm<1><<<dim3(32, 32), 256, 0, stream>>>(o1b, W1b, b1, nullptr, hb, 4096, 1024);
  // y2 = h @ W2^T + b2 + out1   (reuse y1 buffer)
  k_gemm64<2><<<dim3(64, 8), 256, 0, stream>>>(hb, W2b, b2, o1f, y1, 1024, 4096);
  k_ln<false><<<4096, 256, 0, stream>>>(y1, g2, be2, (float*)d_out, nullptr);
}